// Round 1
// baseline (66.517 us; speedup 1.0000x reference)
//
#include <hip/hip_runtime.h>
#include <math.h>

#define NB 32
#define NN 1024
#define NF 512

// ---------------- transpose W[NN][NF] -> Wt[NF][NN] ----------------
__global__ __launch_bounds__(256) void transpose_w_k(const float* __restrict__ W,
                                                     float* __restrict__ Wt) {
    __shared__ float tile[32][33];
    int n0 = blockIdx.x * 32;
    int f0 = blockIdx.y * 32;
    int tx = threadIdx.x & 31;
    int ty = threadIdx.x >> 5;  // 0..7
#pragma unroll
    for (int r = 0; r < 32; r += 8) {
        tile[ty + r][tx] = W[(n0 + ty + r) * NF + (f0 + tx)];
    }
    __syncthreads();
#pragma unroll
    for (int r = 0; r < 32; r += 8) {
        Wt[(f0 + ty + r) * NN + (n0 + tx)] = tile[tx][ty + r];
    }
}

// ---------------- wave (64-lane) butterfly reductions ----------------
// xor-butterfly: every lane ends with the bitwise-identical value
__device__ __forceinline__ float wave_sum(float v) {
#pragma unroll
    for (int d = 1; d < 64; d <<= 1) v += __shfl_xor(v, d, 64);
    return v;
}
__device__ __forceinline__ float wave_max(float v) {
#pragma unroll
    for (int d = 1; d < 64; d <<= 1) v = fmaxf(v, __shfl_xor(v, d, 64));
    return v;
}

// One wave per output (b,f). Solves g(u) = sum_n relu(u - m_n) + relu(u + m_n) = 1
// for m = |x + 0.5W| (plus) and m = |x - 0.5W| (minus); out = relu(u_p - u_m).
__global__ __launch_bounds__(256) void spike_main_k(const float* __restrict__ x,
                                                    const float* __restrict__ W,
                                                    const float* __restrict__ Wt,
                                                    int use_wt,
                                                    float* __restrict__ out) {
    int bid  = blockIdx.x;
    int b    = bid >> 7;     // /128 f-groups
    int fg   = bid & 127;
    int wave = threadIdx.x >> 6;
    int lane = threadIdx.x & 63;
    int f    = fg * 4 + wave;

    float mp[16], mm[16];
    float sum_p = 0.f, sum_m = 0.f, max_p = 0.f, max_m = 0.f;
#pragma unroll
    for (int j = 0; j < 16; ++j) {
        int n = lane + 64 * j;
        float xv = x[b * NN + n];
        float wv = use_wt ? Wt[f * NN + n] : W[n * NF + f];
        float ap = fabsf(xv + 0.5f * wv);
        float am = fabsf(xv - 0.5f * wv);
        mp[j] = ap; mm[j] = am;
        sum_p += ap; sum_m += am;
        max_p = fmaxf(max_p, ap);
        max_m = fmaxf(max_m, am);
    }
    sum_p = wave_sum(sum_p);
    sum_m = wave_sum(sum_m);
    max_p = wave_max(max_p);
    max_m = wave_max(max_m);

    // root <= 0 iff g(0) = sum(m) >= 1  (the overwhelmingly common case)
    const bool neg_p = (sum_p >= 1.0f);
    const bool neg_m = (sum_m >= 1.0f);

    float up = -max_p, um = -max_m;   // g(u0) = 0 <= 1, start below the root
    bool done_p = false, done_m = false;

    for (int it = 0; it < 32; ++it) {
        float sp = 0.f, cp = 0.f, sm = 0.f, cm = 0.f;
        if (!done_p) {
#pragma unroll
            for (int j = 0; j < 16; ++j) {
                float v = up + mp[j];
                sp += fmaxf(v, 0.f);
                cp += (v >= 0.f) ? 1.f : 0.f;
            }
            if (!neg_p) {   // rare: root > 0, need the relu(u - m) terms too
#pragma unroll
                for (int j = 0; j < 16; ++j) {
                    float v = up - mp[j];
                    sp += fmaxf(v, 0.f);
                    cp += (v >= 0.f) ? 1.f : 0.f;
                }
            }
        }
        if (!done_m) {
#pragma unroll
            for (int j = 0; j < 16; ++j) {
                float v = um + mm[j];
                sm += fmaxf(v, 0.f);
                cm += (v >= 0.f) ? 1.f : 0.f;
            }
            if (!neg_m) {
#pragma unroll
                for (int j = 0; j < 16; ++j) {
                    float v = um - mm[j];
                    sm += fmaxf(v, 0.f);
                    cm += (v >= 0.f) ? 1.f : 0.f;
                }
            }
        }
        sp = wave_sum(sp); cp = wave_sum(cp);
        sm = wave_sum(sm); cm = wave_sum(cm);

        if (!done_p) {
            float un = up + (1.0f - sp) / cp;   // cp >= 1 always (max element)
            if (neg_p) un = fminf(un, 0.0f);    // keep formula-valid region
            done_p = (fabsf(un - up) <= 4e-7f);
            up = un;
        }
        if (!done_m) {
            float un = um + (1.0f - sm) / cm;
            if (neg_m) un = fminf(un, 0.0f);
            done_m = (fabsf(un - um) <= 4e-7f);
            um = un;
        }
        if (done_p && done_m) break;   // wave-uniform (butterfly => identical per lane)
    }

    if (lane == 0) out[b * NF + f] = fmaxf(up - um, 0.0f);
}

extern "C" void kernel_launch(void* const* d_in, const int* in_sizes, int n_in,
                              void* d_out, int out_size, void* d_ws, size_t ws_size,
                              hipStream_t stream) {
    const float* x = (const float*)d_in[0];   // 32 x 1024
    const float* W = (const float*)d_in[1];   // 1024 x 512
    float* out = (float*)d_out;               // 32 x 512

    const size_t wt_bytes = (size_t)NN * NF * sizeof(float);
    int use_wt = (ws_size >= wt_bytes) ? 1 : 0;
    float* Wt = (float*)d_ws;

    if (use_wt) {
        dim3 g(NN / 32, NF / 32);  // 32 x 16
        transpose_w_k<<<g, 256, 0, stream>>>(W, Wt);
    }
    spike_main_k<<<NB * (NF / 4), 256, 0, stream>>>(x, W, Wt, use_wt, out);
}

// Round 2
// 31.335 us; speedup vs baseline: 2.1228x; 2.1228x over previous
//
#include <hip/hip_runtime.h>
#include <math.h>

#define NB 32
#define NN 1024
#define NF 512

// ---------------- transpose W[NN][NF] -> Wt[NF][NN] ----------------
__global__ __launch_bounds__(256) void transpose_w_k(const float* __restrict__ W,
                                                     float* __restrict__ Wt) {
    __shared__ float tile[32][33];
    int n0 = blockIdx.x * 32;
    int f0 = blockIdx.y * 32;
    int tx = threadIdx.x & 31;
    int ty = threadIdx.x >> 5;  // 0..7
#pragma unroll
    for (int r = 0; r < 32; r += 8) {
        tile[ty + r][tx] = W[(n0 + ty + r) * NF + (f0 + tx)];
    }
    __syncthreads();
#pragma unroll
    for (int r = 0; r < 32; r += 8) {
        Wt[(f0 + ty + r) * NN + (n0 + tx)] = tile[tx][ty + r];
    }
}

// xor-butterfly: every lane ends with the bitwise-identical sum
__device__ __forceinline__ float wave_sum(float v) {
#pragma unroll
    for (int d = 1; d < 64; d <<= 1) v += __shfl_xor(v, d, 64);
    return v;
}

// masked sum (m >= t) via cndmask; count via ballot+popcount (SALU, no 2nd butterfly)
#define SWEEP_GE(MARR, T, S_OUT, C_OUT)                          \
    {                                                            \
        float _s = 0.f; int _c = 0;                              \
        _Pragma("unroll")                                        \
        for (int _j = 0; _j < 16; ++_j) {                        \
            bool _pr = (MARR[_j] >= (T));                        \
            _c += (int)__popcll(__ballot(_pr));                  \
            _s += _pr ? MARR[_j] : 0.0f;                         \
        }                                                        \
        S_OUT = wave_sum(_s);                                    \
        C_OUT = _c;                                              \
    }

// general-case sweep: elements with m <= u (root > 0 regime; never hit with this data)
#define SWEEP_LE(MARR, U, S_OUT, C_OUT)                          \
    {                                                            \
        float _s = 0.f; int _c = 0;                              \
        _Pragma("unroll")                                        \
        for (int _j = 0; _j < 16; ++_j) {                        \
            bool _pr = (MARR[_j] <= (U));                        \
            _c += (int)__popcll(__ballot(_pr));                  \
            _s += _pr ? MARR[_j] : 0.0f;                         \
        }                                                        \
        S_OUT = wave_sum(_s);                                    \
        C_OUT = _c;                                              \
    }

// One wave per output (b,f). Root of g(u) = sum_n [relu(u - m_n) + relu(u + m_n)] = 1
// for m = |x + 0.5W| (plus) and m = |x - 0.5W| (minus); out = relu(u_p - u_m).
__global__ __launch_bounds__(256) void spike_main_k(const float* __restrict__ x,
                                                    const float* __restrict__ W,
                                                    const float* __restrict__ Wt,
                                                    int use_wt,
                                                    float* __restrict__ out) {
    int bid  = blockIdx.x;
    int b    = bid >> 7;
    int fg   = bid & 127;
    int wave = threadIdx.x >> 6;
    int lane = threadIdx.x & 63;
    int f    = fg * 4 + wave;

    float mp[16], mm[16];
    float sp0 = 0.f, sm0 = 0.f;

    if (use_wt) {
        const float4* x4 = reinterpret_cast<const float4*>(x + (size_t)b * NN);
        const float4* w4 = reinterpret_cast<const float4*>(Wt + (size_t)f * NN);
#pragma unroll
        for (int j = 0; j < 4; ++j) {
            float4 xv = x4[lane + 64 * j];
            float4 wv = w4[lane + 64 * j];
            float ap, am;
            ap = fabsf(xv.x + 0.5f * wv.x); am = fabsf(xv.x - 0.5f * wv.x);
            mp[4*j+0] = ap; mm[4*j+0] = am; sp0 += ap; sm0 += am;
            ap = fabsf(xv.y + 0.5f * wv.y); am = fabsf(xv.y - 0.5f * wv.y);
            mp[4*j+1] = ap; mm[4*j+1] = am; sp0 += ap; sm0 += am;
            ap = fabsf(xv.z + 0.5f * wv.z); am = fabsf(xv.z - 0.5f * wv.z);
            mp[4*j+2] = ap; mm[4*j+2] = am; sp0 += ap; sm0 += am;
            ap = fabsf(xv.w + 0.5f * wv.w); am = fabsf(xv.w - 0.5f * wv.w);
            mp[4*j+3] = ap; mm[4*j+3] = am; sp0 += ap; sm0 += am;
        }
    } else {
#pragma unroll
        for (int j = 0; j < 16; ++j) {
            int n = lane + 64 * j;
            float xv = x[(size_t)b * NN + n];
            float wv = W[(size_t)n * NF + f];
            float ap = fabsf(xv + 0.5f * wv);
            float am = fabsf(xv - 0.5f * wv);
            mp[j] = ap; mm[j] = am;
            sp0 += ap; sm0 += am;
        }
    }
    float Sp = wave_sum(sp0);
    float Sm = wave_sum(sm0);

    const bool neg_p = (Sp >= 1.0f);   // root <= 0 (always true for this data)
    const bool neg_m = (Sm >= 1.0f);

    // free accelerated step 0 from setup stats: quadratic tail model at t=0
    // t1 = 2*(E - sqrt(E))/c with E = S, c = 1024  ->  u = -t1
    float up = neg_p ? (-2.0f * (Sp - sqrtf(Sp)) * (1.0f / 1024.0f))
                     : ((1.0f - Sp) * (1.0f / 1024.0f));
    float um = neg_m ? (-2.0f * (Sm - sqrtf(Sm)) * (1.0f / 1024.0f))
                     : ((1.0f - Sm) * (1.0f / 1024.0f));

    bool done_p = false, done_m = false;
    bool accel_p = true, accel_m = true;   // one more accelerated sweep each

    for (int it = 0; it < 24 && (!done_p || !done_m); ++it) {
        if (!done_p) {
            float S; int c;
            if (neg_p) {
                float t = -up;
                SWEEP_GE(mp, t, S, c);
                if (c == 0) {          // overshot below -max (rare): bisect toward 0
                    up *= 0.5f;
                } else {
                    float fc = (float)c;
                    float unew;
                    if (accel_p) {
                        float E = fmaxf(S + fc * up, 0.0f);
                        unew = up - 2.0f * (E - sqrtf(E)) / fc;
                        accel_p = false;
                    } else {
                        unew = (1.0f - S) / fc;
                        done_p = (unew == up) || (fabsf(unew - up) < 1e-7f);
                    }
                    up = unew;
                }
            } else {                   // general case, root > 0 (never hit here)
                float S2; int c2;
                SWEEP_LE(mp, up, S2, c2);
                float unew = (1.0f - Sp + S2) / (1024.0f + (float)c2);
                done_p = (unew == up) || (fabsf(unew - up) < 1e-7f);
                up = unew;
            }
        }
        if (!done_m) {
            float S; int c;
            if (neg_m) {
                float t = -um;
                SWEEP_GE(mm, t, S, c);
                if (c == 0) {
                    um *= 0.5f;
                } else {
                    float fc = (float)c;
                    float unew;
                    if (accel_m) {
                        float E = fmaxf(S + fc * um, 0.0f);
                        unew = um - 2.0f * (E - sqrtf(E)) / fc;
                        accel_m = false;
                    } else {
                        unew = (1.0f - S) / fc;
                        done_m = (unew == um) || (fabsf(unew - um) < 1e-7f);
                    }
                    um = unew;
                }
            } else {
                float S2; int c2;
                SWEEP_LE(mm, um, S2, c2);
                float unew = (1.0f - Sm + S2) / (1024.0f + (float)c2);
                done_m = (unew == um) || (fabsf(unew - um) < 1e-7f);
                um = unew;
            }
        }
    }

    if (lane == 0) out[(size_t)b * NF + f] = fmaxf(up - um, 0.0f);
}

extern "C" void kernel_launch(void* const* d_in, const int* in_sizes, int n_in,
                              void* d_out, int out_size, void* d_ws, size_t ws_size,
                              hipStream_t stream) {
    const float* x = (const float*)d_in[0];   // 32 x 1024
    const float* W = (const float*)d_in[1];   // 1024 x 512
    float* out = (float*)d_out;               // 32 x 512

    const size_t wt_bytes = (size_t)NN * NF * sizeof(float);
    int use_wt = (ws_size >= wt_bytes) ? 1 : 0;
    float* Wt = (float*)d_ws;

    if (use_wt) {
        dim3 g(NN / 32, NF / 32);  // 32 x 16
        transpose_w_k<<<g, 256, 0, stream>>>(W, Wt);
    }
    spike_main_k<<<NB * (NF / 4), 256, 0, stream>>>(x, W, Wt, use_wt, out);
}